// Round 16
// baseline (95.735 us; speedup 1.0000x reference)
//
#include <hip/hip_runtime.h>
#include <hip/hip_bf16.h>

typedef __attribute__((ext_vector_type(4))) float f32x4;
typedef __attribute__((ext_vector_type(16))) float f32x16;
typedef __attribute__((ext_vector_type(8))) short bf16x8;
typedef __attribute__((ext_vector_type(4))) unsigned int u32x4;

#define MFMA16(a,b,c) __builtin_amdgcn_mfma_f32_16x16x32_bf16(a,b,c,0,0,0)
#define MFMA32(a,b,c) __builtin_amdgcn_mfma_f32_32x32x16_bf16(a,b,c,0,0,0)
#define LOG2E 1.44269504088896340736f

__device__ __forceinline__ float bf2f(unsigned short u){
  unsigned v = ((unsigned)u) << 16;
  float f; __builtin_memcpy(&f, &v, 4); return f;
}
__device__ __forceinline__ unsigned short f2bf(float f){
  unsigned x; __builtin_memcpy(&x, &f, 4);
  x += 0x7fffu + ((x >> 16) & 1u);   // RNE
  return (unsigned short)(x >> 16);
}
__device__ __forceinline__ void gload_lds16(const void* g, void* l){
  __builtin_amdgcn_global_load_lds((const __attribute__((address_space(1))) void*)g,
                                   (__attribute__((address_space(3))) void*)l, 16, 0, 0);
}
__device__ __forceinline__ f32x16 zero16(){
  f32x16 z;
#pragma unroll
  for (int i = 0; i < 16; ++i) z[i] = 0.f;
  return z;
}
__device__ __forceinline__ unsigned cvtpk(float lo, float hi_){
  unsigned d;
  asm("v_cvt_pk_bf16_f32 %0, %1, %2" : "=v"(d) : "v"(lo), "v"(hi_));
  return d;
}
// pack 16 per-lane P values (key map (r&3)+8*(r>>2)+4*hi) into two PV A-frags
__device__ __forceinline__ void pack_group(const float* p, bf16x8& f0, bf16x8& f1){
  unsigned a0 = cvtpk(p[0], p[1]),  b0 = cvtpk(p[4],  p[5]);
  unsigned a1 = cvtpk(p[2], p[3]),  b1 = cvtpk(p[6],  p[7]);
  unsigned c0 = cvtpk(p[8], p[9]),  d0 = cvtpk(p[12], p[13]);
  unsigned c1 = cvtpk(p[10],p[11]), d1 = cvtpk(p[14], p[15]);
  asm("v_permlane32_swap_b32 %0, %1" : "+v"(a0), "+v"(b0));
  asm("v_permlane32_swap_b32 %0, %1" : "+v"(a1), "+v"(b1));
  asm("v_permlane32_swap_b32 %0, %1" : "+v"(c0), "+v"(d0));
  asm("v_permlane32_swap_b32 %0, %1" : "+v"(c1), "+v"(d1));
  u32x4 w0 = {a0, a1, b0, b1};
  u32x4 w1 = {c0, c1, d0, d1};
  f0 = __builtin_bit_cast(bf16x8, w0);
  f1 = __builtin_bit_cast(bf16x8, w1);
}

// ---------------- prep: x-cast + transpose-cast both weights, ONE launch ----------------
__device__ __forceinline__ void castT_body(const float* __restrict__ src,
                                           unsigned short* __restrict__ dst,
                                           const int R, const int C,
                                           const int bx, const int by){
  __shared__ unsigned short t[64][65];
  const int r0 = by * 64, c0 = bx * 64;
  const int tid = threadIdx.x;
#pragma unroll
  for (int i = 0; i < 16; ++i){
    int idx = i*256 + tid; int r = idx >> 6, c = idx & 63;
    t[r][c] = f2bf(src[(size_t)(r0 + r)*C + c0 + c]);
  }
  __syncthreads();
#pragma unroll
  for (int i = 0; i < 16; ++i){
    int idx = i*256 + tid; int c = idx >> 6, r = idx & 63;
    dst[(size_t)(c0 + c)*R + r0 + r] = t[r][c];
  }
}
__global__ void k_prep(const float* __restrict__ x, const float* __restrict__ wa,
                       const float* __restrict__ wp,
                       unsigned short* __restrict__ xb,
                       unsigned short* __restrict__ waT, unsigned short* __restrict__ wpT){
  const int bid = blockIdx.x;
  if (bid < 4096){                             // x-cast: 4 elems/thread
    const int i = bid * 256 + threadIdx.x;
    const float4 v = ((const float4*)x)[i];
    ushort4 o;
    o.x = f2bf(v.x); o.y = f2bf(v.y); o.z = f2bf(v.z); o.w = f2bf(v.w);
    ((ushort4*)xb)[i] = o;
  } else {
    const int wid = bid - 4096;                // 0..1023
    if (wid < 768) castT_body(wa, waT, 1024, 3072, wid % 48, wid / 48);
    else { const int w = wid - 768; castT_body(wp, wpT, 1024, 1024, w % 16, w / 16); }
  }
}

// ======= QKV GEMM v6: 128x256 block tile, wave tile 64x128, BK=32, triple-buffered =======
// Higher arithmetic intensity: 12 ds_read_b128 -> 32 MFMA per wave-K-step (43.7 FLOP/LDS-byte
// vs 32 before). Same v3 sync: wait OWN tile-t loads (vmcnt(6)) before barrier; barrier
// certifies tile (RAW) + iter t-1 reads done (WAR for staging t+2). Chunk swizzle
// ch' = ch ^ ((row>>1)&3) both-sides -> conflict-free ds_read_b128.
__global__ __launch_bounds__(256,2) void k_gemm_qkv(const unsigned short* __restrict__ xb,
    const unsigned short* __restrict__ waT, const float* __restrict__ b_attn,
    unsigned short* __restrict__ qb, unsigned short* __restrict__ kb,
    unsigned short* __restrict__ vb)
{
  __shared__ char lds[73728];                  // 3 bufs x (A 8KB + B 16KB)
  const int K = 1024, NT = 32;
  const int tid = threadIdx.x, lane = tid & 63, wave = tid >> 6;
  const int wr = wave >> 1, wc = wave & 1;
  const int l15 = lane & 15, lg = lane >> 4;
  char* const ldsb = (char*)lds;

  f32x4 acc[4][8];
#pragma unroll
  for (int m = 0; m < 4; ++m)
#pragma unroll
    for (int n = 0; n < 8; ++n) acc[m][n] = (f32x4){0.f,0.f,0.f,0.f};

  // 2D XCD regions: 384 blocks = 8 XCD x 48; each XCD: 8 bm x 6 bn
  const int hh0 = blockIdx.x;
  const int xcd = hh0 & 7, idx = hh0 >> 3;     // idx 0..47
  const int bm = (((xcd >> 1) << 3) + (idx & 7)) * 128;     // 4 M-regions of 8
  const int bn = (((xcd & 1) * 6) + (idx >> 3)) * 256;      // 2 N-regions of 6

  const int o = tid * 16;
  const int srow = o >> 6;                     // 0..63
  const int sch = ((o >> 4) & 3) ^ ((srow >> 1) & 3);
  const unsigned short* gA0 = xb  + (size_t)(bm + srow)*K       + sch*8;
  const unsigned short* gA1 = xb  + (size_t)(bm + 64 + srow)*K  + sch*8;
  const unsigned short* gB0 = waT + (size_t)(bn + srow)*K       + sch*8;
  const unsigned short* gB1 = waT + (size_t)(bn + 64 + srow)*K  + sch*8;
  const unsigned short* gB2 = waT + (size_t)(bn + 128 + srow)*K + sch*8;
  const unsigned short* gB3 = waT + (size_t)(bn + 192 + srow)*K + sch*8;
  const int rsw = (l15 >> 1) & 3;
  const int aoff = (wr*64 + l15)*64 + ((lg ^ rsw) << 4);            // A region [0,8K)
  const int boff = 8192 + (wc*128 + l15)*64 + ((lg ^ rsw) << 4);    // B region [8K,24K)

#define STG6(koff, bb) do { \
    gload_lds16(gA0 + (koff), ldsb + (bb) + o); \
    gload_lds16(gA1 + (koff), ldsb + (bb) + 4096 + o); \
    gload_lds16(gB0 + (koff), ldsb + (bb) + 8192 + o); \
    gload_lds16(gB1 + (koff), ldsb + (bb) + 12288 + o); \
    gload_lds16(gB2 + (koff), ldsb + (bb) + 16384 + o); \
    gload_lds16(gB3 + (koff), ldsb + (bb) + 20480 + o); } while(0)

  STG6(0, 0);
  STG6(32, 24576);
  int bcur = 0, bstg = 49152;
  for (int t = 0; t < NT; ++t){
    if (t + 1 < NT) asm volatile("s_waitcnt vmcnt(6)" ::: "memory");
    else            asm volatile("s_waitcnt vmcnt(0)" ::: "memory");
    __builtin_amdgcn_s_barrier();
    __builtin_amdgcn_sched_barrier(0);
    if (t + 2 < NT) STG6((size_t)(t + 2) << 5, bstg);
    bf16x8 af[4], bg[8];
#pragma unroll
    for (int m = 0; m < 4; ++m) af[m] = *(const bf16x8*)(ldsb + bcur + aoff + m*1024);
#pragma unroll
    for (int n = 0; n < 8; ++n) bg[n] = *(const bf16x8*)(ldsb + bcur + boff + n*1024);
    __builtin_amdgcn_s_setprio(1);
#pragma unroll
    for (int m = 0; m < 4; ++m)
#pragma unroll
      for (int n = 0; n < 8; ++n)
        acc[m][n] = MFMA16(af[m], bg[n], acc[m][n]);
    __builtin_amdgcn_s_setprio(0);
    bcur = (bcur == 49152) ? 0 : bcur + 24576;
    bstg = (bstg == 49152) ? 0 : bstg + 24576;
  }
#undef STG6

  // epilogue: scatter q/k/v (k,v in tiled+swizzled attention layouts)
#pragma unroll
  for (int m = 0; m < 4; ++m){
#pragma unroll
    for (int n = 0; n < 8; ++n){
#pragma unroll
      for (int r = 0; r < 4; ++r){
        const int row = bm + wr*64 + m*16 + lg*4 + r;
        const int col = bn + wc*128 + n*16 + l15;
        const float val = acc[m][n][r] + b_attn[col];
        const int part = col >> 10, c = col & 1023;
        const int h = c >> 6, d = c & 63;
        const int b = row >> 11, t = row & 2047;
        const unsigned short u = f2bf(val);
        const size_t bhbase = (size_t)(b*16 + h)*131072;
        if (part == 0){
          qb[bhbase + (size_t)t*64 + d] = u;
        } else {
          const int tile = t >> 6, l = t & 63;
          const size_t base = bhbase + (size_t)tile*4096;
          if (part == 1) kb[base + l*64 + ((((d>>3)^(l&7))<<3) | (d&7))] = u;   // K[key][d], swz
          else           vb[base + d*64 + ((((l>>3)^(d&7))<<3) | (l&7))] = u;   // V^T[d][key], swz
        }
      }
    }
  }
}

// ======= GEMM mainloop small: 64x128 tile (proj), BK=32, triple-buffered =======
__device__ __forceinline__ void gemm_core_s(const unsigned short* __restrict__ A,
                                            const unsigned short* __restrict__ Bt,
                                            const int K, const int bm, const int bn,
                                            char* ldsb, f32x4 acc[2][4])
{
  const int tid = threadIdx.x, lane = tid & 63, wave = tid >> 6;
  const int wr = wave >> 1, wc = wave & 1;
  const int l15 = lane & 15, lg = lane >> 4;
  const int o = tid * 16;
  const int srow = o >> 6;
  const int sch = ((o >> 4) & 3) ^ ((srow >> 1) & 3);
  const unsigned short* gA0 = A  + (size_t)(bm + srow)*K      + sch*8;
  const unsigned short* gB0 = Bt + (size_t)(bn + srow)*K      + sch*8;
  const unsigned short* gB1 = Bt + (size_t)(bn + 64 + srow)*K + sch*8;
  const int rsw = (l15 >> 1) & 3;
  const int aoff = (wr*32 + l15)*64 + ((lg ^ rsw) << 4);
  const int boff = 4096 + (wc*64 + l15)*64 + ((lg ^ rsw) << 4);

#define STGS(koff, bb) do { \
    gload_lds16(gA0 + (koff), ldsb + (bb) + o); \
    gload_lds16(gB0 + (koff), ldsb + (bb) + 4096 + o); \
    gload_lds16(gB1 + (koff), ldsb + (bb) + 8192 + o); } while(0)

  const int NT = K >> 5;
  STGS(0, 0);
  STGS(32, 12288);
  int bcur = 0, bstg = 24576;
  for (int t = 0; t < NT; ++t){
    if (t + 1 < NT) asm volatile("s_waitcnt vmcnt(3)" ::: "memory");
    else            asm volatile("s_waitcnt vmcnt(0)" ::: "memory");
    __builtin_amdgcn_s_barrier();
    __builtin_amdgcn_sched_barrier(0);
    if (t + 2 < NT) STGS((size_t)(t + 2) << 5, bstg);
    bf16x8 af[2], bg[4];
#pragma unroll
    for (int m = 0; m < 2; ++m) af[m] = *(const bf16x8*)(ldsb + bcur + aoff + m*1024);
#pragma unroll
    for (int n = 0; n < 4; ++n) bg[n] = *(const bf16x8*)(ldsb + bcur + boff + n*1024);
    __builtin_amdgcn_s_setprio(1);
#pragma unroll
    for (int m = 0; m < 2; ++m)
#pragma unroll
      for (int n = 0; n < 4; ++n)
        acc[m][n] = MFMA16(af[m], bg[n], acc[m][n]);
    __builtin_amdgcn_s_setprio(0);
    bcur = (bcur == 24576) ? 0 : bcur + 12288;
    bstg = (bstg == 24576) ? 0 : bstg + 12288;
  }
#undef STGS
}

// ---------------- proj GEMM: yb[4096][1024] @ wpT -> out fp32 + bias (64x128 tiles) ----------------
__global__ __launch_bounds__(256,4) void k_gemm_proj(const unsigned short* __restrict__ yb,
    const unsigned short* __restrict__ wpT, const float* __restrict__ b_proj,
    float* __restrict__ out)
{
  __shared__ char lds[36864];
  f32x4 acc[2][4];
#pragma unroll
  for (int m = 0; m < 2; ++m)
#pragma unroll
    for (int n = 0; n < 4; ++n) acc[m][n] = (f32x4){0.f,0.f,0.f,0.f};
  int wgid = blockIdx.y * 8 + blockIdx.x;
  wgid = (wgid & 7) * 64 + (wgid >> 3);
  const int bm = (wgid / 8) * 64, bn = (wgid % 8) * 128;
  gemm_core_s(yb, wpT, 1024, bm, bn, lds, acc);
  const int lane = threadIdx.x & 63, wave = threadIdx.x >> 6;
  const int wr = wave >> 1, wc = wave & 1, l15 = lane & 15, lg = lane >> 4;
#pragma unroll
  for (int m = 0; m < 2; ++m){
#pragma unroll
    for (int n = 0; n < 4; ++n){
#pragma unroll
      for (int r = 0; r < 4; ++r){
        const int row = bm + wr*32 + m*16 + lg*4 + r;
        const int col = bn + wc*64 + n*16 + l15;
        out[(size_t)row*1024 + col] = acc[m][n][r] + b_proj[col];
      }
    }
  }
}

// ---------------- flash attention: 4 waves/block, lsum via ones-MFMA ----------------
__global__ __launch_bounds__(256,2) void k_attn(const unsigned short* __restrict__ q,
                       const unsigned short* __restrict__ kt,
                       const unsigned short* __restrict__ vt,
                       unsigned short* __restrict__ y)
{
  __shared__ char lds[32768];
  const int tid = threadIdx.x, lane = tid & 63, wave = tid >> 6;
  const int l31 = lane & 31, hi = lane >> 5;
  const int i = blockIdx.x, ii = i & 255;
  const int bh = ii & 31;
  const int qbi = (i < 256) ? (15 - (ii >> 5)) : (ii >> 5);
  const int q0w = qbi*128 + wave*32;
  const int ntiles = (qbi + 1) * 2;
  const unsigned short* qh = q + (size_t)bh * 131072;
  const char* kbase = (const char*)(kt + (size_t)bh * 131072);
  const char* vbase = (const char*)(vt + (size_t)bh * 131072);

  const float C = 0.125f * LOG2E;
  const float M = 16.0f;
  const bf16x8 ones = {0x3F80,0x3F80,0x3F80,0x3F80,0x3F80,0x3F80,0x3F80,0x3F80};

  bf16x8 qf[4];
  {
    const unsigned short* qp = qh + (size_t)(q0w + l31)*64 + hi*8;
#pragma unroll
    for (int ds = 0; ds < 4; ++ds) qf[ds] = *(const bf16x8*)(qp + ds*16);
  }

  f32x16 yac0 = zero16(), yac1 = zero16(), yacl = zero16();
  const int mask_from = q0w >> 6;
  const int stg = tid * 16;
  const int dst = wave * 1024;
  char* ldsK = lds;
  char* ldsV = lds + 16384;

#define STAGE(tile, buf) do { \
    const char* ks_ = kbase + (size_t)(tile)*8192; \
    const char* vs_ = vbase + (size_t)(tile)*8192; \
    gload_lds16(ks_ + stg,        ldsK + (buf)*8192 + dst); \
    gload_lds16(ks_ + 4096 + stg, ldsK + (buf)*8192 + 4096 + dst); \
    gload_lds16(vs_ + stg,        ldsV + (buf)*8192 + dst); \
    gload_lds16(vs_ + 4096 + stg, ldsV + (buf)*8192 + 4096 + dst); \
  } while(0)

  STAGE(0, 0);
  __syncthreads();

  const int swz = (l31 & 7) << 4;
  const int rowb = l31 * 128;

  for (int t = 0; t < ntiles; ++t){
    const int buf = t & 1;
    if (t + 1 < ntiles) STAGE(t + 1, buf ^ 1);

    const char* kb_ = ldsK + buf*8192;
    const char* vb_ = ldsV + buf*8192;

    bf16x8 kf[8];
#pragma unroll
    for (int ds = 0; ds < 4; ++ds){
      const int ch = ((ds*2 + hi) << 4) ^ swz;
      kf[ds]   = *(const bf16x8*)(kb_ + rowb + ch);
      kf[ds+4] = *(const bf16x8*)(kb_ + 4096 + rowb + ch);
    }
    f32x16 s0 = zero16(), s1 = zero16();
#pragma unroll
    for (int ds = 0; ds < 4; ++ds){
      s0 = MFMA32(kf[ds],   qf[ds], s0);
      s1 = MFMA32(kf[ds+4], qf[ds], s1);
    }

    bf16x8 vf[8];
#pragma unroll
    for (int ks = 0; ks < 4; ++ks){
      const int ch = ((ks*2 + hi) << 4) ^ swz;
      vf[ks]   = *(const bf16x8*)(vb_ + rowb + ch);
      vf[ks+4] = *(const bf16x8*)(vb_ + 4096 + rowb + ch);
    }

    if (t >= mask_from){
      const int qg = q0w + l31, key0 = t << 6;
#pragma unroll
      for (int r = 0; r < 16; ++r){
        const int kl = (r&3) + 8*(r>>2) + 4*hi;
        if (key0 + kl      > qg) s0[r] = -1e30f;
        if (key0 + 32 + kl > qg) s1[r] = -1e30f;
      }
    }

    float p0[16], p1[16];
#pragma unroll
    for (int r = 0; r < 16; ++r){
      p0[r] = __builtin_amdgcn_exp2f(__builtin_fmaf(s0[r], C, -M));
      p1[r] = __builtin_amdgcn_exp2f(__builtin_fmaf(s1[r], C, -M));
    }

    bf16x8 pa[4];
    pack_group(p0, pa[0], pa[1]);
    pack_group(p1, pa[2], pa[3]);
#pragma unroll
    for (int ks = 0; ks < 4; ++ks){
      yac0 = MFMA32(pa[ks], vf[ks],   yac0);
      yac1 = MFMA32(pa[ks], vf[ks+4], yac1);
      yacl = MFMA32(pa[ks], ones,     yacl);   // row-sum of P on the matrix pipe
    }
    __syncthreads();
  }
#undef STAGE

  const int b = bh >> 4, h = bh & 15;
  unsigned short* yp = y + ((size_t)b*2048 + q0w)*1024 + h*64;
#pragma unroll
  for (int r = 0; r < 16; ++r){
    const int ql = (r&3) + 8*(r>>2) + 4*hi;
    const float li = __builtin_amdgcn_rcpf(yacl[r]);   // lsum already row-aligned: no shfl
    yp[(size_t)ql*1024 + l31]      = f2bf(yac0[r] * li);
    yp[(size_t)ql*1024 + 32 + l31] = f2bf(yac1[r] * li);
  }
}

extern "C" void kernel_launch(void* const* d_in, const int* in_sizes, int n_in,
                              void* d_out, int out_size, void* d_ws, size_t ws_size,
                              hipStream_t stream) {
  const float* x      = (const float*)d_in[0];
  const float* w_attn = (const float*)d_in[1];
  const float* b_attn = (const float*)d_in[2];
  const float* w_proj = (const float*)d_in[3];
  const float* b_proj = (const float*)d_in[4];
  float* out = (float*)d_out;

  unsigned short* ws  = (unsigned short*)d_ws;
  unsigned short* xb  = ws;                    // 4096x1024
  unsigned short* waT = xb  + 4194304;         // 3072x1024
  unsigned short* wpT = waT + 3145728;         // 1024x1024
  unsigned short* qb  = wpT + 1048576;         // [B,H,T,D]
  unsigned short* kb  = qb  + 4194304;         // [B,H][tile][64key][64d] swz
  unsigned short* vb  = kb  + 4194304;         // [B,H][tile][64d][64key] swz
  unsigned short* yb  = vb  + 4194304;         // 4096x1024

  k_prep<<<dim3(5120), dim3(256), 0, stream>>>(x, w_attn, w_proj, xb, waT, wpT);
  k_gemm_qkv<<<dim3(384), dim3(256), 0, stream>>>(xb, waT, b_attn, qb, kb, vb);
  k_attn<<<dim3(512), dim3(256), 0, stream>>>(qb, kb, vb, yb);
  k_gemm_proj<<<dim3(8,64), dim3(256), 0, stream>>>(yb, wpT, b_proj, out);
}

// Round 17
// 93.721 us; speedup vs baseline: 1.0215x; 1.0215x over previous
//
#include <hip/hip_runtime.h>
#include <hip/hip_bf16.h>

typedef __attribute__((ext_vector_type(4))) float f32x4;
typedef __attribute__((ext_vector_type(16))) float f32x16;
typedef __attribute__((ext_vector_type(8))) short bf16x8;
typedef __attribute__((ext_vector_type(4))) unsigned int u32x4;

#define MFMA16(a,b,c) __builtin_amdgcn_mfma_f32_16x16x32_bf16(a,b,c,0,0,0)
#define MFMA32(a,b,c) __builtin_amdgcn_mfma_f32_32x32x16_bf16(a,b,c,0,0,0)
#define LOG2E 1.44269504088896340736f

__device__ __forceinline__ float bf2f(unsigned short u){
  unsigned v = ((unsigned)u) << 16;
  float f; __builtin_memcpy(&f, &v, 4); return f;
}
__device__ __forceinline__ unsigned short f2bf(float f){
  unsigned x; __builtin_memcpy(&x, &f, 4);
  x += 0x7fffu + ((x >> 16) & 1u);   // RNE
  return (unsigned short)(x >> 16);
}
__device__ __forceinline__ void gload_lds16(const void* g, void* l){
  __builtin_amdgcn_global_load_lds((const __attribute__((address_space(1))) void*)g,
                                   (__attribute__((address_space(3))) void*)l, 16, 0, 0);
}
__device__ __forceinline__ f32x16 zero16(){
  f32x16 z;
#pragma unroll
  for (int i = 0; i < 16; ++i) z[i] = 0.f;
  return z;
}
__device__ __forceinline__ unsigned cvtpk(float lo, float hi_){
  unsigned d;
  asm("v_cvt_pk_bf16_f32 %0, %1, %2" : "=v"(d) : "v"(lo), "v"(hi_));
  return d;
}
// pack 16 per-lane P values (key map (r&3)+8*(r>>2)+4*hi) into two PV A-frags
__device__ __forceinline__ void pack_group(const float* p, bf16x8& f0, bf16x8& f1){
  unsigned a0 = cvtpk(p[0], p[1]),  b0 = cvtpk(p[4],  p[5]);
  unsigned a1 = cvtpk(p[2], p[3]),  b1 = cvtpk(p[6],  p[7]);
  unsigned c0 = cvtpk(p[8], p[9]),  d0 = cvtpk(p[12], p[13]);
  unsigned c1 = cvtpk(p[10],p[11]), d1 = cvtpk(p[14], p[15]);
  asm("v_permlane32_swap_b32 %0, %1" : "+v"(a0), "+v"(b0));
  asm("v_permlane32_swap_b32 %0, %1" : "+v"(a1), "+v"(b1));
  asm("v_permlane32_swap_b32 %0, %1" : "+v"(c0), "+v"(d0));
  asm("v_permlane32_swap_b32 %0, %1" : "+v"(c1), "+v"(d1));
  u32x4 w0 = {a0, a1, b0, b1};
  u32x4 w1 = {c0, c1, d0, d1};
  f0 = __builtin_bit_cast(bf16x8, w0);
  f1 = __builtin_bit_cast(bf16x8, w1);
}

// ---------------- prep: x-cast + transpose-cast both weights, ONE launch ----------------
__device__ __forceinline__ void castT_body(const float* __restrict__ src,
                                           unsigned short* __restrict__ dst,
                                           const int R, const int C,
                                           const int bx, const int by){
  __shared__ unsigned short t[64][65];
  const int r0 = by * 64, c0 = bx * 64;
  const int tid = threadIdx.x;
#pragma unroll
  for (int i = 0; i < 16; ++i){
    int idx = i*256 + tid; int r = idx >> 6, c = idx & 63;
    t[r][c] = f2bf(src[(size_t)(r0 + r)*C + c0 + c]);
  }
  __syncthreads();
#pragma unroll
  for (int i = 0; i < 16; ++i){
    int idx = i*256 + tid; int c = idx >> 6, r = idx & 63;
    dst[(size_t)(c0 + c)*R + r0 + r] = t[r][c];
  }
}
__global__ void k_prep(const float* __restrict__ x, const float* __restrict__ wa,
                       const float* __restrict__ wp,
                       unsigned short* __restrict__ xb,
                       unsigned short* __restrict__ waT, unsigned short* __restrict__ wpT){
  const int bid = blockIdx.x;
  if (bid < 4096){                             // x-cast: 4 elems/thread
    const int i = bid * 256 + threadIdx.x;
    const float4 v = ((const float4*)x)[i];
    ushort4 o;
    o.x = f2bf(v.x); o.y = f2bf(v.y); o.z = f2bf(v.z); o.w = f2bf(v.w);
    ((ushort4*)xb)[i] = o;
  } else {
    const int wid = bid - 4096;                // 0..1023
    if (wid < 768) castT_body(wa, waT, 1024, 3072, wid % 48, wid / 48);
    else { const int w = wid - 768; castT_body(wp, wpT, 1024, 1024, w % 16, w / 16); }
  }
}

// ======= GEMM mainloop v3: 128x128 tile, BK=32, TRIPLE-buffered LDS, 1 barrier/K-step =======
// LDS-read-throughput-bound at the measured 85 B/cyc/CU ds_read_b128 ceiling:
// 96 KB/CU-round -> ~1129 cy, matching measured 1150 cy/round-slot. Structural ceiling
// for a 32-FLOP/LDS-byte (64x64 wave-tile) schedule.
__device__ __forceinline__ void gemm_core3(const unsigned short* __restrict__ A,
                                           const unsigned short* __restrict__ Bt,
                                           const int K, const int bm, const int bn,
                                           char* ldsb, f32x4 acc[4][4])
{
  const int tid = threadIdx.x, lane = tid & 63, wave = tid >> 6;
  const int wr = wave >> 1, wc = wave & 1;
  const int l15 = lane & 15, lg = lane >> 4;
  const int o = tid * 16;
  const int srow = o >> 6;
  const int sch = ((o >> 4) & 3) ^ ((srow >> 1) & 3);
  const unsigned short* gA0 = A  + (size_t)(bm + srow)*K      + sch*8;
  const unsigned short* gA1 = A  + (size_t)(bm + 64 + srow)*K + sch*8;
  const unsigned short* gB0 = Bt + (size_t)(bn + srow)*K      + sch*8;
  const unsigned short* gB1 = Bt + (size_t)(bn + 64 + srow)*K + sch*8;
  const int rsw = (l15 >> 1) & 3;
  const int aoff = (wr*64 + l15)*64 + ((lg ^ rsw) << 4);
  const int boff = 8192 + (wc*64 + l15)*64 + ((lg ^ rsw) << 4);

#define STG3(koff, bb) do { \
    gload_lds16(gA0 + (koff), ldsb + (bb) + o); \
    gload_lds16(gA1 + (koff), ldsb + (bb) + 4096 + o); \
    gload_lds16(gB0 + (koff), ldsb + (bb) + 8192 + o); \
    gload_lds16(gB1 + (koff), ldsb + (bb) + 12288 + o); } while(0)

  const int NT = K >> 5;
  STG3(0, 0);
  STG3(32, 16384);
  int bcur = 0, bstg = 32768;
  for (int t = 0; t < NT; ++t){
    if (t + 1 < NT) asm volatile("s_waitcnt vmcnt(4)" ::: "memory");
    else            asm volatile("s_waitcnt vmcnt(0)" ::: "memory");
    __builtin_amdgcn_s_barrier();
    __builtin_amdgcn_sched_barrier(0);
    if (t + 2 < NT) STG3((size_t)(t + 2) << 5, bstg);
    bf16x8 af[4], bg[4];
#pragma unroll
    for (int m = 0; m < 4; ++m) af[m] = *(const bf16x8*)(ldsb + bcur + aoff + m*1024);
#pragma unroll
    for (int n = 0; n < 4; ++n) bg[n] = *(const bf16x8*)(ldsb + bcur + boff + n*1024);
    __builtin_amdgcn_s_setprio(1);
#pragma unroll
    for (int m = 0; m < 4; ++m)
#pragma unroll
      for (int n = 0; n < 4; ++n)
        acc[m][n] = MFMA16(af[m], bg[n], acc[m][n]);
    __builtin_amdgcn_s_setprio(0);
    bcur = (bcur == 32768) ? 0 : bcur + 16384;
    bstg = (bstg == 32768) ? 0 : bstg + 16384;
  }
#undef STG3
}

// ---------------- QKV GEMM: xb[4096][1024] @ waT -> q [B,H,T,D]; k,v tiled-swizzled ----------------
__global__ __launch_bounds__(256,3) void k_gemm_qkv(const unsigned short* __restrict__ xb,
    const unsigned short* __restrict__ waT, const float* __restrict__ b_attn,
    unsigned short* __restrict__ qb, unsigned short* __restrict__ kb,
    unsigned short* __restrict__ vb)
{
  __shared__ char lds[49152];
  f32x4 acc[4][4];
#pragma unroll
  for (int m = 0; m < 4; ++m)
#pragma unroll
    for (int n = 0; n < 4; ++n) acc[m][n] = (f32x4){0.f,0.f,0.f,0.f};
  // 2D XCD regions (FETCH 57->21MB, R11)
  const int hh0 = blockIdx.y * 24 + blockIdx.x;
  const int xcd = hh0 & 7, idx = hh0 >> 3;
  const int bm = (((xcd >> 1) << 3) + (idx & 7)) * 128;
  const int bn = ((xcd & 1) * 12 + (idx >> 3)) * 128;
  gemm_core3(xb, waT, 1024, bm, bn, lds, acc);
  const int lane = threadIdx.x & 63, wave = threadIdx.x >> 6;
  const int wr = wave >> 1, wc = wave & 1, l15 = lane & 15, lg = lane >> 4;
#pragma unroll
  for (int m = 0; m < 4; ++m){
#pragma unroll
    for (int n = 0; n < 4; ++n){
#pragma unroll
      for (int r = 0; r < 4; ++r){
        const int row = bm + wr*64 + m*16 + lg*4 + r;
        const int col = bn + wc*64 + n*16 + l15;
        const float val = acc[m][n][r] + b_attn[col];
        const int part = col >> 10, c = col & 1023;
        const int h = c >> 6, d = c & 63;
        const int b = row >> 11, t = row & 2047;
        const unsigned short u = f2bf(val);
        const size_t bhbase = (size_t)(b*16 + h)*131072;
        if (part == 0){
          qb[bhbase + (size_t)t*64 + d] = u;
        } else {
          const int tile = t >> 6, l = t & 63;
          const size_t base = bhbase + (size_t)tile*4096;
          if (part == 1) kb[base + l*64 + ((((d>>3)^(l&7))<<3) | (d&7))] = u;   // K[key][d], swz
          else           vb[base + d*64 + ((((l>>3)^(d&7))<<3) | (l&7))] = u;   // V^T[d][key], swz
        }
      }
    }
  }
}

// ======= GEMM mainloop small: 64x128 tile (proj), BK=32, triple-buffered =======
__device__ __forceinline__ void gemm_core_s(const unsigned short* __restrict__ A,
                                            const unsigned short* __restrict__ Bt,
                                            const int K, const int bm, const int bn,
                                            char* ldsb, f32x4 acc[2][4])
{
  const int tid = threadIdx.x, lane = tid & 63, wave = tid >> 6;
  const int wr = wave >> 1, wc = wave & 1;
  const int l15 = lane & 15, lg = lane >> 4;
  const int o = tid * 16;
  const int srow = o >> 6;
  const int sch = ((o >> 4) & 3) ^ ((srow >> 1) & 3);
  const unsigned short* gA0 = A  + (size_t)(bm + srow)*K      + sch*8;
  const unsigned short* gB0 = Bt + (size_t)(bn + srow)*K      + sch*8;
  const unsigned short* gB1 = Bt + (size_t)(bn + 64 + srow)*K + sch*8;
  const int rsw = (l15 >> 1) & 3;
  const int aoff = (wr*32 + l15)*64 + ((lg ^ rsw) << 4);
  const int boff = 4096 + (wc*64 + l15)*64 + ((lg ^ rsw) << 4);

#define STGS(koff, bb) do { \
    gload_lds16(gA0 + (koff), ldsb + (bb) + o); \
    gload_lds16(gB0 + (koff), ldsb + (bb) + 4096 + o); \
    gload_lds16(gB1 + (koff), ldsb + (bb) + 8192 + o); } while(0)

  const int NT = K >> 5;
  STGS(0, 0);
  STGS(32, 12288);
  int bcur = 0, bstg = 24576;
  for (int t = 0; t < NT; ++t){
    if (t + 1 < NT) asm volatile("s_waitcnt vmcnt(3)" ::: "memory");
    else            asm volatile("s_waitcnt vmcnt(0)" ::: "memory");
    __builtin_amdgcn_s_barrier();
    __builtin_amdgcn_sched_barrier(0);
    if (t + 2 < NT) STGS((size_t)(t + 2) << 5, bstg);
    bf16x8 af[2], bg[4];
#pragma unroll
    for (int m = 0; m < 2; ++m) af[m] = *(const bf16x8*)(ldsb + bcur + aoff + m*1024);
#pragma unroll
    for (int n = 0; n < 4; ++n) bg[n] = *(const bf16x8*)(ldsb + bcur + boff + n*1024);
    __builtin_amdgcn_s_setprio(1);
#pragma unroll
    for (int m = 0; m < 2; ++m)
#pragma unroll
      for (int n = 0; n < 4; ++n)
        acc[m][n] = MFMA16(af[m], bg[n], acc[m][n]);
    __builtin_amdgcn_s_setprio(0);
    bcur = (bcur == 24576) ? 0 : bcur + 12288;
    bstg = (bstg == 24576) ? 0 : bstg + 12288;
  }
#undef STGS
}

// ---------------- proj GEMM: yb[4096][1024] @ wpT -> out fp32 + bias (64x128 tiles) ----------------
__global__ __launch_bounds__(256,4) void k_gemm_proj(const unsigned short* __restrict__ yb,
    const unsigned short* __restrict__ wpT, const float* __restrict__ b_proj,
    float* __restrict__ out)
{
  __shared__ char lds[36864];
  f32x4 acc[2][4];
#pragma unroll
  for (int m = 0; m < 2; ++m)
#pragma unroll
    for (int n = 0; n < 4; ++n) acc[m][n] = (f32x4){0.f,0.f,0.f,0.f};
  int wgid = blockIdx.y * 8 + blockIdx.x;
  wgid = (wgid & 7) * 64 + (wgid >> 3);
  const int bm = (wgid / 8) * 64, bn = (wgid % 8) * 128;
  gemm_core_s(yb, wpT, 1024, bm, bn, lds, acc);
  const int lane = threadIdx.x & 63, wave = threadIdx.x >> 6;
  const int wr = wave >> 1, wc = wave & 1, l15 = lane & 15, lg = lane >> 4;
#pragma unroll
  for (int m = 0; m < 2; ++m){
#pragma unroll
    for (int n = 0; n < 4; ++n){
#pragma unroll
      for (int r = 0; r < 4; ++r){
        const int row = bm + wr*32 + m*16 + lg*4 + r;
        const int col = bn + wc*64 + n*16 + l15;
        out[(size_t)row*1024 + col] = acc[m][n][r] + b_proj[col];
      }
    }
  }
}

// ---------------- flash attention: 4 waves/block, lsum via ones-MFMA ----------------
__global__ __launch_bounds__(256,2) void k_attn(const unsigned short* __restrict__ q,
                       const unsigned short* __restrict__ kt,
                       const unsigned short* __restrict__ vt,
                       unsigned short* __restrict__ y)
{
  __shared__ char lds[32768];
  const int tid = threadIdx.x, lane = tid & 63, wave = tid >> 6;
  const int l31 = lane & 31, hi = lane >> 5;
  const int i = blockIdx.x, ii = i & 255;
  const int bh = ii & 31;
  const int qbi = (i < 256) ? (15 - (ii >> 5)) : (ii >> 5);
  const int q0w = qbi*128 + wave*32;
  const int ntiles = (qbi + 1) * 2;
  const unsigned short* qh = q + (size_t)bh * 131072;
  const char* kbase = (const char*)(kt + (size_t)bh * 131072);
  const char* vbase = (const char*)(vt + (size_t)bh * 131072);

  const float C = 0.125f * LOG2E;
  const float M = 16.0f;
  const bf16x8 ones = {0x3F80,0x3F80,0x3F80,0x3F80,0x3F80,0x3F80,0x3F80,0x3F80};

  bf16x8 qf[4];
  {
    const unsigned short* qp = qh + (size_t)(q0w + l31)*64 + hi*8;
#pragma unroll
    for (int ds = 0; ds < 4; ++ds) qf[ds] = *(const bf16x8*)(qp + ds*16);
  }

  f32x16 yac0 = zero16(), yac1 = zero16(), yacl = zero16();
  const int mask_from = q0w >> 6;
  const int stg = tid * 16;
  const int dst = wave * 1024;
  char* ldsK = lds;
  char* ldsV = lds + 16384;

#define STAGE(tile, buf) do { \
    const char* ks_ = kbase + (size_t)(tile)*8192; \
    const char* vs_ = vbase + (size_t)(tile)*8192; \
    gload_lds16(ks_ + stg,        ldsK + (buf)*8192 + dst); \
    gload_lds16(ks_ + 4096 + stg, ldsK + (buf)*8192 + 4096 + dst); \
    gload_lds16(vs_ + stg,        ldsV + (buf)*8192 + dst); \
    gload_lds16(vs_ + 4096 + stg, ldsV + (buf)*8192 + 4096 + dst); \
  } while(0)

  STAGE(0, 0);
  __syncthreads();

  const int swz = (l31 & 7) << 4;
  const int rowb = l31 * 128;

  for (int t = 0; t < ntiles; ++t){
    const int buf = t & 1;
    if (t + 1 < ntiles) STAGE(t + 1, buf ^ 1);

    const char* kb_ = ldsK + buf*8192;
    const char* vb_ = ldsV + buf*8192;

    bf16x8 kf[8];
#pragma unroll
    for (int ds = 0; ds < 4; ++ds){
      const int ch = ((ds*2 + hi) << 4) ^ swz;
      kf[ds]   = *(const bf16x8*)(kb_ + rowb + ch);
      kf[ds+4] = *(const bf16x8*)(kb_ + 4096 + rowb + ch);
    }
    f32x16 s0 = zero16(), s1 = zero16();
#pragma unroll
    for (int ds = 0; ds < 4; ++ds){
      s0 = MFMA32(kf[ds],   qf[ds], s0);
      s1 = MFMA32(kf[ds+4], qf[ds], s1);
    }

    bf16x8 vf[8];
#pragma unroll
    for (int ks = 0; ks < 4; ++ks){
      const int ch = ((ks*2 + hi) << 4) ^ swz;
      vf[ks]   = *(const bf16x8*)(vb_ + rowb + ch);
      vf[ks+4] = *(const bf16x8*)(vb_ + 4096 + rowb + ch);
    }

    if (t >= mask_from){
      const int qg = q0w + l31, key0 = t << 6;
#pragma unroll
      for (int r = 0; r < 16; ++r){
        const int kl = (r&3) + 8*(r>>2) + 4*hi;
        if (key0 + kl      > qg) s0[r] = -1e30f;
        if (key0 + 32 + kl > qg) s1[r] = -1e30f;
      }
    }

    float p0[16], p1[16];
#pragma unroll
    for (int r = 0; r < 16; ++r){
      p0[r] = __builtin_amdgcn_exp2f(__builtin_fmaf(s0[r], C, -M));
      p1[r] = __builtin_amdgcn_exp2f(__builtin_fmaf(s1[r], C, -M));
    }

    bf16x8 pa[4];
    pack_group(p0, pa[0], pa[1]);
    pack_group(p1, pa[2], pa[3]);
#pragma unroll
    for (int ks = 0; ks < 4; ++ks){
      yac0 = MFMA32(pa[ks], vf[ks],   yac0);
      yac1 = MFMA32(pa[ks], vf[ks+4], yac1);
      yacl = MFMA32(pa[ks], ones,     yacl);   // row-sum of P on the matrix pipe
    }
    __syncthreads();
  }
#undef STAGE

  const int b = bh >> 4, h = bh & 15;
  unsigned short* yp = y + ((size_t)b*2048 + q0w)*1024 + h*64;
#pragma unroll
  for (int r = 0; r < 16; ++r){
    const int ql = (r&3) + 8*(r>>2) + 4*hi;
    const float li = __builtin_amdgcn_rcpf(yacl[r]);   // lsum already row-aligned: no shfl
    yp[(size_t)ql*1024 + l31]      = f2bf(yac0[r] * li);
    yp[(size_t)ql*1024 + 32 + l31] = f2bf(yac1[r] * li);
  }
}

extern "C" void kernel_launch(void* const* d_in, const int* in_sizes, int n_in,
                              void* d_out, int out_size, void* d_ws, size_t ws_size,
                              hipStream_t stream) {
  const float* x      = (const float*)d_in[0];
  const float* w_attn = (const float*)d_in[1];
  const float* b_attn = (const float*)d_in[2];
  const float* w_proj = (const float*)d_in[3];
  const float* b_proj = (const float*)d_in[4];
  float* out = (float*)d_out;

  unsigned short* ws  = (unsigned short*)d_ws;
  unsigned short* xb  = ws;                    // 4096x1024
  unsigned short* waT = xb  + 4194304;         // 3072x1024
  unsigned short* wpT = waT + 3145728;         // 1024x1024
  unsigned short* qb  = wpT + 1048576;         // [B,H,T,D]
  unsigned short* kb  = qb  + 4194304;         // [B,H][tile][64key][64d] swz
  unsigned short* vb  = kb  + 4194304;         // [B,H][tile][64d][64key] swz
  unsigned short* yb  = vb  + 4194304;         // 4096x1024

  k_prep<<<dim3(5120), dim3(256), 0, stream>>>(x, w_attn, w_proj, xb, waT, wpT);
  k_gemm_qkv<<<dim3(24,32), dim3(256), 0, stream>>>(xb, waT, b_attn, qb, kb, vb);
  k_attn<<<dim3(512), dim3(256), 0, stream>>>(qb, kb, vb, yb);
  k_gemm_proj<<<dim3(8,64), dim3(256), 0, stream>>>(yb, wpT, b_proj, out);
}